// Round 6
// baseline (204.281 us; speedup 1.0000x reference)
//
#include <hip/hip_runtime.h>
#include <hip/hip_bf16.h>
#include <stdint.h>
#include <stddef.h>

typedef __attribute__((ext_vector_type(8))) short s8v;       // 8 x bf16 (as i16)
typedef __attribute__((ext_vector_type(4))) float f32x4;
typedef __attribute__((ext_vector_type(4))) uint32_t u32x4;
typedef __attribute__((ext_vector_type(4))) unsigned short u16x4;

#define KDIM 4096
#define NH   128
#define MMEM 50000
#define BFEAT 64
#define NGRP 3125               // 50000 / 16 row-groups, exact
#define NBLK 256                // one block per CU, perfect balance
#define NGMAX 13                // max groups per block (53 blocks have 13, rest 12)
#define NSEG 8                  // argmin M-segments

static __device__ __forceinline__ unsigned short f2bf(float f) {
  union { float f; uint32_t u; } c; c.f = f;
  uint32_t u = c.u;
  return (unsigned short)((u + 0x7FFFu + ((u >> 16) & 1u)) >> 16);  // RNE
}

static __device__ __forceinline__ short f2bfs(float f) {
  __hip_bfloat16 h = __float2bfloat16(f);   // pairs fuse to v_cvt_pk_bf16_f32
  short s;
  __builtin_memcpy(&s, &h, sizeof(s));
  return s;
}

// ---- Kernel 0 (fused): hash_W f32->bf16  |  hf feature codes  |  keys init --
__global__ __launch_bounds__(256) void prep_kernel(
    const float* __restrict__ W, unsigned short* __restrict__ Wb,
    const float* __restrict__ flat, const float* __restrict__ hb,
    unsigned char* __restrict__ hf_bytes, unsigned int* __restrict__ keys) {
  const int bid = blockIdx.x;
  const int t   = threadIdx.x;
  if (bid < 512) {                      // ---- convert part: 512 blocks ----
    if (bid == 0 && t < BFEAT) keys[t] = 0xFFFFFFFFu;
    int i = bid * 256 + t;              // float4 index, 131072 total
    f32x4 v = reinterpret_cast<const f32x4*>(W)[i];
    u16x4 o;
    o[0] = f2bf(v[0]); o[1] = f2bf(v[1]); o[2] = f2bf(v[2]); o[3] = f2bf(v[3]);
    reinterpret_cast<u16x4*>(Wb)[i] = o;
  } else {                              // ---- hf part: 2048 blocks x 4 dots ----
    int did  = (bid - 512) * 4 + (t >> 6);   // 8192 dots
    int n = did & 127, b = did >> 7;
    int lane = t & 63;
    const f32x4* fa = reinterpret_cast<const f32x4*>(flat + (size_t)b * KDIM);
    const f32x4* wa = reinterpret_cast<const f32x4*>(W + (size_t)n * KDIM);
    float s = 0.f;
#pragma unroll 4
    for (int q = 0; q < 16; ++q) {
      f32x4 x = fa[lane + 64 * q], y = wa[lane + 64 * q];
      s += x[0] * y[0] + x[1] * y[1] + x[2] * y[2] + x[3] * y[3];
    }
    for (int o = 32; o; o >>= 1) s += __shfl_down(s, o, 64);
    if (lane == 0) hf_bytes[b * NH + n] = (s + hb[n] - 0.5f) > 0.f ? 1 : 0;
  }
}

// ---- Kernel A: persistent balanced streaming MFMA, paired-chunk A bursts ----
// 256 blocks x 512 threads, block owns 12-13 groups of 16 rows, acc resident.
// Even steps issue A-loads for chunks s+2 AND s+3 back-to-back -> per-row
// 512B contiguous DRAM bursts (page-activation amortization). B reg-direct
// from L2 every step. Sync: lgkmcnt(0) + raw s_barrier (no vmcnt drain).

__global__ __launch_bounds__(512, 2) void hash_bits_kernel(
    const float* __restrict__ A,
    const unsigned short* __restrict__ Wb,
    const float* __restrict__ hb,
    uint32_t* __restrict__ out_bits) {
  __shared__ short Abuf[2][NGMAX * 16 * 64];       // 2 x 26 KB bf16, swizzled
  __shared__ unsigned short smb[NGMAX * 16][8];    // epilogue u16 slices

  const int t    = threadIdx.x;
  const int lane = t & 63;
  const int w    = t >> 6;          // wave 0..7 -> cols 16w..16w+15
  const int l15  = lane & 15;
  const int kq   = lane >> 4;
  const int b    = blockIdx.x;
  const int g0   = (b * NGRP) >> 8;
  const int NG   = (((b + 1) * NGRP) >> 8) - g0;   // 12 or 13
  const int row0 = g0 * 16;

  // ---- staging geometry: pair P = t + 512p -> 32B of one row ----
  const float* srcA[4];
  int ldsoff[4];
#pragma unroll
  for (int p = 0; p < 4; ++p) {
    int P  = t + 512 * p;
    int g  = P >> 7;
    int q  = P & 127;
    int r  = q >> 3;
    int kg = q & 7;
    srcA[p]   = A + (size_t)(row0 + g * 16 + r) * KDIM + kg * 8;
    ldsoff[p] = (g * 16 + r) * 64 + ((kg ^ (r & 7)) << 3);
  }
  const bool v3 = (t + 1536) < NG * 128;   // p=3 validity (p<3 always valid)

  const unsigned short* pb = Wb + (size_t)(16 * w + l15) * KDIM + kq * 8;
  const float hbv = hb[16 * w + l15];

  f32x4 acc[NGMAX];
#pragma unroll
  for (int g = 0; g < NGMAX; ++g) acc[g] = (f32x4){0.f, 0.f, 0.f, 0.f};

  f32x4 aRA[4][2], aRB[4][2];     // A-reg sets: even chunks -> aRA, odd -> aRB
  s8v bA0, bA1, bB0, bB1;         // B-frag sets: even chunks -> bA, odd -> bB

#define LOADA_TO(SET, CH) do {                                                \
  const f32x4* q0 = reinterpret_cast<const f32x4*>(srcA[0] + (CH) * 64);      \
  SET[0][0] = q0[0]; SET[0][1] = q0[1];                                       \
  const f32x4* q1 = reinterpret_cast<const f32x4*>(srcA[1] + (CH) * 64);      \
  SET[1][0] = q1[0]; SET[1][1] = q1[1];                                       \
  const f32x4* q2 = reinterpret_cast<const f32x4*>(srcA[2] + (CH) * 64);      \
  SET[2][0] = q2[0]; SET[2][1] = q2[1];                                       \
  if (v3) {                                                                   \
    const f32x4* q3 = reinterpret_cast<const f32x4*>(srcA[3] + (CH) * 64);    \
    SET[3][0] = q3[0]; SET[3][1] = q3[1];                                     \
  }                                                                           \
} while (0)

#define CVTW1(SET, P, BUFW) do {                                              \
  s8v av;                                                                     \
  av[0] = f2bfs(SET[P][0][0]); av[1] = f2bfs(SET[P][0][1]);                   \
  av[2] = f2bfs(SET[P][0][2]); av[3] = f2bfs(SET[P][0][3]);                   \
  av[4] = f2bfs(SET[P][1][0]); av[5] = f2bfs(SET[P][1][1]);                   \
  av[6] = f2bfs(SET[P][1][2]); av[7] = f2bfs(SET[P][1][3]);                   \
  *reinterpret_cast<s8v*>(&(BUFW)[ldsoff[P]]) = av;                           \
} while (0)

#define CVTWRITE(SET, BUFW) do {                                              \
  CVTW1(SET, 0, BUFW); CVTW1(SET, 1, BUFW); CVTW1(SET, 2, BUFW);              \
  if (v3) CVTW1(SET, 3, BUFW);                                                \
} while (0)

#define LOADB(CH, B0, B1) do {                                                \
  B0 = *reinterpret_cast<const s8v*>(pb + (CH) * 64);                         \
  B1 = *reinterpret_cast<const s8v*>(pb + (CH) * 64 + 32);                    \
} while (0)

#define COMPUTE(BUFR, B0, B1) do {                                            \
  _Pragma("unroll")                                                           \
  for (int g = 0; g < NGMAX; ++g) {                                           \
    const s8v af = *reinterpret_cast<const s8v*>(                             \
        &(BUFR)[(g * 16 + l15) * 64 + ((kq ^ (l15 & 7)) << 3)]);              \
    acc[g] = __builtin_amdgcn_mfma_f32_16x16x32_bf16(af, B0, acc[g], 0, 0, 0);\
  }                                                                           \
  _Pragma("unroll")                                                           \
  for (int g = 0; g < NGMAX; ++g) {                                           \
    const s8v af = *reinterpret_cast<const s8v*>(                             \
        &(BUFR)[(g * 16 + l15) * 64 + (((4 + kq) ^ (l15 & 7)) << 3)]);        \
    acc[g] = __builtin_amdgcn_mfma_f32_16x16x32_bf16(af, B1, acc[g], 0, 0, 0);\
  }                                                                           \
} while (0)

#define BARRIER() do {                                                        \
  asm volatile("s_waitcnt lgkmcnt(0)" ::: "memory");                          \
  __builtin_amdgcn_s_barrier();                                               \
  __builtin_amdgcn_sched_barrier(0);                                          \
} while (0)

  // Prologue: A(0)->aRA->LDS buf0; A(1)->aRB; B(0)->bA; B(1)->bB
  LOADA_TO(aRA, 0);
  CVTWRITE(aRA, Abuf[0]);
  LOADA_TO(aRB, 1);
  LOADB(0, bA0, bA1);
  LOADB(1, bB0, bB1);

  for (int s2 = 0; s2 < 64; s2 += 2) {
    // ---- even step s2: compute s2, stage s2+1, burst-issue A(s2+2,s2+3) ----
    BARRIER();
    COMPUTE(Abuf[0], bA0, bA1);
    if (s2 + 1 < 64) CVTWRITE(aRB, Abuf[1]);
    if (s2 + 3 < 64) { LOADA_TO(aRA, s2 + 2); LOADA_TO(aRB, s2 + 3); }
    if (s2 + 2 < 64) LOADB(s2 + 2, bA0, bA1);
    // ---- odd step s2+1: compute s2+1, stage s2+2 ----
    BARRIER();
    COMPUTE(Abuf[1], bB0, bB1);
    if (s2 + 2 < 64) CVTWRITE(aRA, Abuf[0]);
    if (s2 + 3 < 64) LOADB(s2 + 3, bB0, bB1);
  }

  // ---- epilogue: sign -> ballot -> u16 slices -> packed 128-bit rows ----
#pragma unroll
  for (int g = 0; g < NGMAX; ++g) {
#pragma unroll
    for (int r = 0; r < 4; ++r) {
      uint64_t mask = __ballot(acc[g][r] + hbv - 0.5f > 0.f);
      if (l15 == r)
        smb[g * 16 + (lane >> 4) * 4 + r][w] =
            (unsigned short)((mask >> (16 * (lane >> 4))) & 0xFFFFu);
    }
  }
  __syncthreads();
  const int rows = NG * 16;
  if (t < rows) {
    uint32_t w0 = (uint32_t)smb[t][0] | ((uint32_t)smb[t][1] << 16);
    uint32_t w1 = (uint32_t)smb[t][2] | ((uint32_t)smb[t][3] << 16);
    uint32_t w2 = (uint32_t)smb[t][4] | ((uint32_t)smb[t][5] << 16);
    uint32_t w3 = (uint32_t)smb[t][6] | ((uint32_t)smb[t][7] << 16);
    reinterpret_cast<u32x4*>(out_bits)[row0 + t] = (u32x4){w0, w1, w2, w3};
  }
}

// ---- Kernel B: segmented argmin Hamming (ref tie-break) via atomicMin -------
__global__ __launch_bounds__(256) void argmin_part_kernel(
    const uint32_t* __restrict__ hm_bits, const unsigned char* __restrict__ hf_bytes,
    int M, unsigned int* __restrict__ keys) {
  __shared__ uint32_t red[256];
  const int b   = blockIdx.x & (BFEAT - 1);
  const int seg = blockIdx.x / BFEAT;
  const int span = (M + NSEG - 1) / NSEG;
  const int m0 = seg * span;
  int m1 = m0 + span; if (m1 > M) m1 = M;
  const int t = threadIdx.x;
  uint64_t hf0 = 0, hf1 = 0;
  const unsigned char* hfb = hf_bytes + b * NH;
  for (int c = 0; c < 64; ++c) {
    hf0 |= (uint64_t)(hfb[c] & 1u) << c;
    hf1 |= (uint64_t)(hfb[c + 64] & 1u) << c;
  }
  int hfsum = __popcll(hf0) + __popcll(hf1);
  uint32_t best = 0xFFFFFFFFu;
  for (int m = m0 + t; m < m1; m += 256) {
    u32x4 pv = reinterpret_cast<const u32x4*>(hm_bits)[m];
    uint64_t h0 = (uint64_t)pv[0] | ((uint64_t)pv[1] << 32);
    uint64_t h1 = (uint64_t)pv[2] | ((uint64_t)pv[3] << 32);
    int hmsum = __popcll(h0) + __popcll(h1);
    int dot   = __popcll(h0 & hf0) + __popcll(h1 & hf1);
    int hd    = hfsum + hmsum - 2 * dot;
    uint32_t key = ((uint32_t)hd << 16) | (uint32_t)m;   // M < 65536, HD <= 256
    best = best < key ? best : key;
  }
  red[t] = best;
  __syncthreads();
  for (int s = 128; s > 0; s >>= 1) {
    if (t < s) red[t] = red[t] < red[t + s] ? red[t] : red[t + s];
    __syncthreads();
  }
  if (t == 0) atomicMin(&keys[b], red[0]);   // device-scope, order-independent
}

// ---- Kernel C: gather nearest memory rows -----------------------------------
__global__ __launch_bounds__(256) void gather_kernel(
    const float* __restrict__ memory, const unsigned int* __restrict__ keys,
    float* __restrict__ out) {
  int b = blockIdx.x;
  int t = threadIdx.x;
  int m = (int)(keys[b] & 0xFFFFu);
  const f32x4* src = reinterpret_cast<const f32x4*>(memory + (size_t)m * KDIM);
  f32x4* dst = reinterpret_cast<f32x4*>(out + (size_t)b * KDIM);
#pragma unroll
  for (int c = 0; c < 4; ++c) dst[t + 256 * c] = src[t + 256 * c];
}

extern "C" void kernel_launch(void* const* d_in, const int* in_sizes, int n_in,
                              void* d_out, int out_size, void* d_ws, size_t ws_size,
                              hipStream_t stream) {
  const float* feature = (const float*)d_in[0];   // [64,64,8,8] == [64,4096]
  const float* memory  = (const float*)d_in[1];   // [50000,4096]
  const float* hash_W  = (const float*)d_in[2];   // [128,4096]
  const float* hash_b  = (const float*)d_in[3];   // [128]
  float* out = (float*)d_out;

  char* ws = (char*)d_ws;
  unsigned short* Wb       = (unsigned short*)ws;                       // 1,048,576 B
  uint32_t*       hm_bits  = (uint32_t*)(ws + 1048576);                 //   800,000 B
  unsigned char*  hf_bytes = (unsigned char*)(ws + 1048576 + 800000);   //     8,192 B
  unsigned int*   keys     = (unsigned int*)(ws + 1048576 + 800000 + 8192); //   256 B

  prep_kernel<<<2560, 256, 0, stream>>>(hash_W, Wb, feature, hash_b, hf_bytes, keys);
  hash_bits_kernel<<<NBLK, 512, 0, stream>>>(memory, Wb, hash_b, hm_bits);
  argmin_part_kernel<<<BFEAT * NSEG, 256, 0, stream>>>(hm_bits, hf_bytes, MMEM, keys);
  gather_kernel<<<BFEAT, 256, 0, stream>>>(memory, keys, out);
}

// Round 7
// 175.814 us; speedup vs baseline: 1.1619x; 1.1619x over previous
//
#include <hip/hip_runtime.h>
#include <hip/hip_bf16.h>
#include <stdint.h>
#include <stddef.h>

typedef __attribute__((ext_vector_type(8))) short s8v;       // 8 x bf16 (as i16)
typedef __attribute__((ext_vector_type(4))) float f32x4;
typedef __attribute__((ext_vector_type(4))) uint32_t u32x4;
typedef __attribute__((ext_vector_type(4))) unsigned short u16x4;

#define KDIM 4096
#define NH   128
#define MMEM 50000
#define BFEAT 64
#define NGRP 3125               // 50000 / 16 row-groups, exact
#define NBLK 256                // one block per CU, perfect balance
#define NGMAX 13                // max groups per block (53 blocks have 13, rest 12)
#define NSEG 8                  // argmin M-segments

static __device__ __forceinline__ unsigned short f2bf(float f) {
  union { float f; uint32_t u; } c; c.f = f;
  uint32_t u = c.u;
  return (unsigned short)((u + 0x7FFFu + ((u >> 16) & 1u)) >> 16);  // RNE
}

static __device__ __forceinline__ short f2bfs(float f) {
  __hip_bfloat16 h = __float2bfloat16(f);   // pairs fuse to v_cvt_pk_bf16_f32
  short s;
  __builtin_memcpy(&s, &h, sizeof(s));
  return s;
}

// ---- Kernel 0 (fused): hash_W f32->bf16  |  hf feature codes  |  keys init --
__global__ __launch_bounds__(256) void prep_kernel(
    const float* __restrict__ W, unsigned short* __restrict__ Wb,
    const float* __restrict__ flat, const float* __restrict__ hb,
    unsigned char* __restrict__ hf_bytes, unsigned int* __restrict__ keys) {
  const int bid = blockIdx.x;
  const int t   = threadIdx.x;
  if (bid < 512) {                      // ---- convert part: 512 blocks ----
    if (bid == 0 && t < BFEAT) keys[t] = 0xFFFFFFFFu;
    int i = bid * 256 + t;              // float4 index, 131072 total
    f32x4 v = reinterpret_cast<const f32x4*>(W)[i];
    u16x4 o;
    o[0] = f2bf(v[0]); o[1] = f2bf(v[1]); o[2] = f2bf(v[2]); o[3] = f2bf(v[3]);
    reinterpret_cast<u16x4*>(Wb)[i] = o;
  } else {                              // ---- hf part: 2048 blocks x 4 dots ----
    int did  = (bid - 512) * 4 + (t >> 6);   // 8192 dots
    int n = did & 127, b = did >> 7;
    int lane = t & 63;
    const f32x4* fa = reinterpret_cast<const f32x4*>(flat + (size_t)b * KDIM);
    const f32x4* wa = reinterpret_cast<const f32x4*>(W + (size_t)n * KDIM);
    float s = 0.f;
#pragma unroll 4
    for (int q = 0; q < 16; ++q) {
      f32x4 x = fa[lane + 64 * q], y = wa[lane + 64 * q];
      s += x[0] * y[0] + x[1] * y[1] + x[2] * y[2] + x[3] * y[3];
    }
    for (int o = 32; o; o >>= 1) s += __shfl_down(s, o, 64);
    if (lane == 0) hf_bytes[b * NH + n] = (s + hb[n] - 0.5f) > 0.f ? 1 : 0;
  }
}

// ---- Kernel A: persistent balanced streaming MFMA (R5 structure) ------------
// 256 blocks x 512 threads, block owns 12-13 groups of 16 rows, acc resident.
// NEW (R7): per-block K-phase offset koff = b & 63 de-phases the K-sweep
// across blocks so the instantaneous address stream covers all 64 k-windows
// (HBM channel spreading). Sum-order change only: |delta| ~1e-6 vs 0.48 margin.
// Sync: lgkmcnt(0) + raw s_barrier only (no vmcnt drain; compiler counts).

__global__ __launch_bounds__(512, 2) void hash_bits_kernel(
    const float* __restrict__ A,
    const unsigned short* __restrict__ Wb,
    const float* __restrict__ hb,
    uint32_t* __restrict__ out_bits) {
  __shared__ short Abuf[2][NGMAX * 16 * 64];       // 2 x 26 KB bf16, swizzled
  __shared__ unsigned short smb[NGMAX * 16][8];    // epilogue u16 slices

  const int t    = threadIdx.x;
  const int lane = t & 63;
  const int w    = t >> 6;          // wave 0..7 -> cols 16w..16w+15
  const int l15  = lane & 15;
  const int kq   = lane >> 4;
  const int b    = blockIdx.x;
  const int koff = b & 63;          // K-phase stagger
  const int g0   = (b * NGRP) >> 8;
  const int NG   = (((b + 1) * NGRP) >> 8) - g0;   // 12 or 13
  const int row0 = g0 * 16;

  // ---- staging geometry: pair P = t + 512p -> 32B of one row ----
  const float* srcA[4];
  int ldsoff[4];
#pragma unroll
  for (int p = 0; p < 4; ++p) {
    int P  = t + 512 * p;
    int g  = P >> 7;
    int q  = P & 127;
    int r  = q >> 3;
    int kg = q & 7;
    srcA[p]   = A + (size_t)(row0 + g * 16 + r) * KDIM + kg * 8;
    ldsoff[p] = (g * 16 + r) * 64 + ((kg ^ (r & 7)) << 3);
  }
  const bool v3 = (t + 1536) < NG * 128;   // p=3 validity (p<3 always valid)

  const unsigned short* pb = Wb + (size_t)(16 * w + l15) * KDIM + kq * 8;
  const float hbv = hb[16 * w + l15];

  f32x4 acc[NGMAX];
#pragma unroll
  for (int g = 0; g < NGMAX; ++g) acc[g] = (f32x4){0.f, 0.f, 0.f, 0.f};

  f32x4 aR[4][2];
  s8v bA0, bA1, bB0, bB1;    // B-frag ring x2 (static regs, rule #20)

#define PCH(S) (((S) + koff) & 63)   // logical step -> physical chunk

#define LOADA(CH) do {                                                        \
  const f32x4* q0 = reinterpret_cast<const f32x4*>(srcA[0] + (CH) * 64);      \
  aR[0][0] = q0[0]; aR[0][1] = q0[1];                                         \
  const f32x4* q1 = reinterpret_cast<const f32x4*>(srcA[1] + (CH) * 64);      \
  aR[1][0] = q1[0]; aR[1][1] = q1[1];                                         \
  const f32x4* q2 = reinterpret_cast<const f32x4*>(srcA[2] + (CH) * 64);      \
  aR[2][0] = q2[0]; aR[2][1] = q2[1];                                         \
  if (v3) {                                                                   \
    const f32x4* q3 = reinterpret_cast<const f32x4*>(srcA[3] + (CH) * 64);    \
    aR[3][0] = q3[0]; aR[3][1] = q3[1];                                       \
  }                                                                           \
} while (0)

#define CVTW1(P, BUFW) do {                                                   \
  s8v av;                                                                     \
  av[0] = f2bfs(aR[P][0][0]); av[1] = f2bfs(aR[P][0][1]);                     \
  av[2] = f2bfs(aR[P][0][2]); av[3] = f2bfs(aR[P][0][3]);                     \
  av[4] = f2bfs(aR[P][1][0]); av[5] = f2bfs(aR[P][1][1]);                     \
  av[6] = f2bfs(aR[P][1][2]); av[7] = f2bfs(aR[P][1][3]);                     \
  *reinterpret_cast<s8v*>(&(BUFW)[ldsoff[P]]) = av;                           \
} while (0)

#define CVTWRITE(BUFW) do {                                                   \
  CVTW1(0, BUFW); CVTW1(1, BUFW); CVTW1(2, BUFW);                             \
  if (v3) CVTW1(3, BUFW);                                                     \
} while (0)

#define LOADB(CH, B0, B1) do {                                                \
  B0 = *reinterpret_cast<const s8v*>(pb + (CH) * 64);                         \
  B1 = *reinterpret_cast<const s8v*>(pb + (CH) * 64 + 32);                    \
} while (0)

#define COMPUTE(BUFR, B0, B1) do {                                            \
  _Pragma("unroll")                                                           \
  for (int g = 0; g < NGMAX; ++g) {                                           \
    const s8v af = *reinterpret_cast<const s8v*>(                             \
        &(BUFR)[(g * 16 + l15) * 64 + ((kq ^ (l15 & 7)) << 3)]);              \
    acc[g] = __builtin_amdgcn_mfma_f32_16x16x32_bf16(af, B0, acc[g], 0, 0, 0);\
  }                                                                           \
  _Pragma("unroll")                                                           \
  for (int g = 0; g < NGMAX; ++g) {                                           \
    const s8v af = *reinterpret_cast<const s8v*>(                             \
        &(BUFR)[(g * 16 + l15) * 64 + (((4 + kq) ^ (l15 & 7)) << 3)]);        \
    acc[g] = __builtin_amdgcn_mfma_f32_16x16x32_bf16(af, B1, acc[g], 0, 0, 0);\
  }                                                                           \
} while (0)

#define BARRIER() do {                                                        \
  asm volatile("s_waitcnt lgkmcnt(0)" ::: "memory");                          \
  __builtin_amdgcn_s_barrier();                                               \
  __builtin_amdgcn_sched_barrier(0);                                          \
} while (0)

// One pipeline step, logical chunk S: barrier | compute S | cvt+write S+1 | issue S+2
#define STEP(S, BUFR, BUFW, B0, B1) do {                                      \
  BARRIER();                                                                  \
  COMPUTE(BUFR, B0, B1);                                                      \
  if ((S) + 1 < 64) CVTWRITE(BUFW);                                           \
  if ((S) + 2 < 64) { LOADA(PCH((S) + 2)); LOADB(PCH((S) + 2), B0, B1); }     \
} while (0)

  // Prologue: A(0) -> LDS buf0; A(1) -> regs; B(0),B(1) -> reg sets
  LOADA(PCH(0));
  CVTWRITE(Abuf[0]);
  LOADA(PCH(1));
  LOADB(PCH(0), bA0, bA1);
  LOADB(PCH(1), bB0, bB1);

  for (int s2 = 0; s2 < 64; s2 += 2) {
    STEP(s2 + 0, Abuf[0], Abuf[1], bA0, bA1);
    STEP(s2 + 1, Abuf[1], Abuf[0], bB0, bB1);
  }

  // ---- epilogue: sign -> ballot -> u16 slices -> packed 128-bit rows ----
#pragma unroll
  for (int g = 0; g < NGMAX; ++g) {
#pragma unroll
    for (int r = 0; r < 4; ++r) {
      uint64_t mask = __ballot(acc[g][r] + hbv - 0.5f > 0.f);
      if (l15 == r)
        smb[g * 16 + (lane >> 4) * 4 + r][w] =
            (unsigned short)((mask >> (16 * (lane >> 4))) & 0xFFFFu);
    }
  }
  __syncthreads();
  const int rows = NG * 16;
  if (t < rows) {
    uint32_t w0 = (uint32_t)smb[t][0] | ((uint32_t)smb[t][1] << 16);
    uint32_t w1 = (uint32_t)smb[t][2] | ((uint32_t)smb[t][3] << 16);
    uint32_t w2 = (uint32_t)smb[t][4] | ((uint32_t)smb[t][5] << 16);
    uint32_t w3 = (uint32_t)smb[t][6] | ((uint32_t)smb[t][7] << 16);
    reinterpret_cast<u32x4*>(out_bits)[row0 + t] = (u32x4){w0, w1, w2, w3};
  }
}

// ---- Kernel B: segmented argmin Hamming (ref tie-break) via atomicMin -------
__global__ __launch_bounds__(256) void argmin_part_kernel(
    const uint32_t* __restrict__ hm_bits, const unsigned char* __restrict__ hf_bytes,
    int M, unsigned int* __restrict__ keys) {
  __shared__ uint32_t red[256];
  const int b   = blockIdx.x & (BFEAT - 1);
  const int seg = blockIdx.x / BFEAT;
  const int span = (M + NSEG - 1) / NSEG;
  const int m0 = seg * span;
  int m1 = m0 + span; if (m1 > M) m1 = M;
  const int t = threadIdx.x;
  uint64_t hf0 = 0, hf1 = 0;
  const unsigned char* hfb = hf_bytes + b * NH;
  for (int c = 0; c < 64; ++c) {
    hf0 |= (uint64_t)(hfb[c] & 1u) << c;
    hf1 |= (uint64_t)(hfb[c + 64] & 1u) << c;
  }
  int hfsum = __popcll(hf0) + __popcll(hf1);
  uint32_t best = 0xFFFFFFFFu;
  for (int m = m0 + t; m < m1; m += 256) {
    u32x4 pv = reinterpret_cast<const u32x4*>(hm_bits)[m];
    uint64_t h0 = (uint64_t)pv[0] | ((uint64_t)pv[1] << 32);
    uint64_t h1 = (uint64_t)pv[2] | ((uint64_t)pv[3] << 32);
    int hmsum = __popcll(h0) + __popcll(h1);
    int dot   = __popcll(h0 & hf0) + __popcll(h1 & hf1);
    int hd    = hfsum + hmsum - 2 * dot;
    uint32_t key = ((uint32_t)hd << 16) | (uint32_t)m;   // M < 65536, HD <= 256
    best = best < key ? best : key;
  }
  red[t] = best;
  __syncthreads();
  for (int s = 128; s > 0; s >>= 1) {
    if (t < s) red[t] = red[t] < red[t + s] ? red[t] : red[t + s];
    __syncthreads();
  }
  if (t == 0) atomicMin(&keys[b], red[0]);   // device-scope, order-independent
}

// ---- Kernel C: gather nearest memory rows -----------------------------------
__global__ __launch_bounds__(256) void gather_kernel(
    const float* __restrict__ memory, const unsigned int* __restrict__ keys,
    float* __restrict__ out) {
  int b = blockIdx.x;
  int t = threadIdx.x;
  int m = (int)(keys[b] & 0xFFFFu);
  const f32x4* src = reinterpret_cast<const f32x4*>(memory + (size_t)m * KDIM);
  f32x4* dst = reinterpret_cast<f32x4*>(out + (size_t)b * KDIM);
#pragma unroll
  for (int c = 0; c < 4; ++c) dst[t + 256 * c] = src[t + 256 * c];
}

extern "C" void kernel_launch(void* const* d_in, const int* in_sizes, int n_in,
                              void* d_out, int out_size, void* d_ws, size_t ws_size,
                              hipStream_t stream) {
  const float* feature = (const float*)d_in[0];   // [64,64,8,8] == [64,4096]
  const float* memory  = (const float*)d_in[1];   // [50000,4096]
  const float* hash_W  = (const float*)d_in[2];   // [128,4096]
  const float* hash_b  = (const float*)d_in[3];   // [128]
  float* out = (float*)d_out;

  char* ws = (char*)d_ws;
  unsigned short* Wb       = (unsigned short*)ws;                       // 1,048,576 B
  uint32_t*       hm_bits  = (uint32_t*)(ws + 1048576);                 //   800,000 B
  unsigned char*  hf_bytes = (unsigned char*)(ws + 1048576 + 800000);   //     8,192 B
  unsigned int*   keys     = (unsigned int*)(ws + 1048576 + 800000 + 8192); //   256 B

  prep_kernel<<<2560, 256, 0, stream>>>(hash_W, Wb, feature, hash_b, hf_bytes, keys);
  hash_bits_kernel<<<NBLK, 512, 0, stream>>>(memory, Wb, hash_b, hm_bits);
  argmin_part_kernel<<<BFEAT * NSEG, 256, 0, stream>>>(hm_bits, hf_bytes, MMEM, keys);
  gather_kernel<<<BFEAT, 256, 0, stream>>>(memory, keys, out);
}